// Round 2
// baseline (652.430 us; speedup 1.0000x reference)
//
#include <hip/hip_runtime.h>

#define DEVI __device__ __forceinline__

typedef _Float16 h8 __attribute__((ext_vector_type(8)));
typedef short s8x __attribute__((ext_vector_type(8)));
typedef float f4 __attribute__((ext_vector_type(4)));

constexpr int NB = 16;     // batches
constexpr int LQ = 2048;
constexpr int LK = 2048;
constexpr int DD = 1024;

DEVI void gld16(void* lds, const void* g) {
  // global -> LDS direct DMA, 16B per lane. LDS dest is wave-uniform base + lane*16.
  // Direct casts => clang emits proper addrspacecast (NOT inttoptr bit-reinterpret).
  __builtin_amdgcn_global_load_lds(
      (const __attribute__((address_space(1))) unsigned int*)g,
      (__attribute__((address_space(3))) unsigned int*)lds, 16, 0, 0);
}

DEVI unsigned short f2bf(float f) {  // RTNE, inputs are finite non-negative here
  union { float f; unsigned int u; } x{f};
  unsigned int r = (x.u + 0x7fffu + ((x.u >> 16) & 1u)) >> 16;
  return (unsigned short)r;
}

// ---------------- k0a: fp32 -> fp16 elementwise (Q, K) ----------------
__global__ __launch_bounds__(256) void k_cvt_h(const float* __restrict__ src,
                                               _Float16* __restrict__ dst, long n4) {
  long i = (long)blockIdx.x * blockDim.x + threadIdx.x;
  long stride = (long)gridDim.x * blockDim.x;
  for (; i < n4; i += stride) {
    float4 v = ((const float4*)src)[i];
    union { _Float16 h[4]; short4 s; } u;
    u.h[0] = (_Float16)v.x; u.h[1] = (_Float16)v.y;
    u.h[2] = (_Float16)v.z; u.h[3] = (_Float16)v.w;
    ((short4*)dst)[i] = u.s;
  }
}

// ---------------- k0b: V fp32 [LK][D] -> VT bf16 [D][LK] (per batch) ----------------
__global__ __launch_bounds__(256) void k_vt(const float* __restrict__ V,
                                            unsigned short* __restrict__ VT,
                                            const int* __restrict__ key_len, int b0) {
  __shared__ float tile[64][65];
  int bl = blockIdx.z;
  int kl = key_len[b0 + bl];
  int k0 = blockIdx.x * 64, d0 = blockIdx.y * 64;
  if (kl != 0 && k0 >= ((kl + 31) & ~31)) return;  // PV never reads these columns
  const float* Vb = V + (size_t)(b0 + bl) * LK * DD;
  unsigned short* VTb = VT + (size_t)bl * DD * LK;
  int t = threadIdx.x;
  int c = t & 63, r4 = t >> 6;
#pragma unroll
  for (int p = 0; p < 16; ++p) {
    int r = p * 4 + r4;
    tile[r][c] = Vb[(size_t)(k0 + r) * DD + d0 + c];
  }
  __syncthreads();
  int c16 = t & 15, r16 = t >> 4;
#pragma unroll
  for (int p = 0; p < 4; ++p) {
    int dr = p * 16 + r16;
    ushort4 u;
    u.x = f2bf(tile[c16 * 4 + 0][dr]);
    u.y = f2bf(tile[c16 * 4 + 1][dr]);
    u.z = f2bf(tile[c16 * 4 + 2][dr]);
    u.w = f2bf(tile[c16 * 4 + 3][dr]);
    *(ushort4*)&VTb[(size_t)(d0 + dr) * LK + k0 + c16 * 4] = u;
  }
}

// ---------------- k1: S = Qh * Kh^T  (fp16 MFMA, 128x128 tile, BK=32) ----------------
__global__ __launch_bounds__(256, 2) void k_qk(const _Float16* __restrict__ Qh,
                                               const _Float16* __restrict__ Kh,
                                               float* __restrict__ S,
                                               const int* __restrict__ key_len, int b0) {
  int bl = blockIdx.z;
  int kl = key_len[b0 + bl];
  int k0t = blockIdx.y * 128;
  if (k0t >= kl) return;  // fully-masked key tile (also covers kl==0)
  __shared__ _Float16 As[128 * 32], Bs[128 * 32];
  const _Float16* Qb = Qh + (size_t)bl * LQ * DD + (size_t)blockIdx.x * 128 * DD;
  const _Float16* Kb = Kh + (size_t)bl * LK * DD + (size_t)k0t * DD;
  float* Sb = S + (size_t)bl * LQ * LK;
  int t = threadIdx.x, lane = t & 63, w = t >> 6;
  int wm = w >> 1, wn = w & 1;
  int srow = t >> 2, scol = (t & 3) * 8;
  int l15 = lane & 15, l4 = lane >> 4;
  f4 acc[4][4] = {};
  for (int kk = 0; kk < DD; kk += 32) {
    gld16((char*)As + t * 16, Qb + (size_t)srow * DD + kk + scol);
    gld16((char*)As + 4096 + t * 16, Qb + (size_t)(64 + srow) * DD + kk + scol);
    gld16((char*)Bs + t * 16, Kb + (size_t)srow * DD + kk + scol);
    gld16((char*)Bs + 4096 + t * 16, Kb + (size_t)(64 + srow) * DD + kk + scol);
    __syncthreads();
    h8 a[4], b[4];
#pragma unroll
    for (int i = 0; i < 4; ++i)
      a[i] = *(const h8*)&As[(wm * 64 + i * 16 + l15) * 32 + l4 * 8];
#pragma unroll
    for (int j = 0; j < 4; ++j)
      b[j] = *(const h8*)&Bs[(wn * 64 + j * 16 + l15) * 32 + l4 * 8];
#pragma unroll
    for (int i = 0; i < 4; ++i)
#pragma unroll
      for (int j = 0; j < 4; ++j)
        acc[i][j] = __builtin_amdgcn_mfma_f32_16x16x32_f16(a[i], b[j], acc[i][j], 0, 0, 0);
    __syncthreads();
  }
  int q0 = blockIdx.x * 128 + wm * 64;
  int c0 = k0t + wn * 64;
#pragma unroll
  for (int i = 0; i < 4; ++i) {
#pragma unroll
    for (int nf = 0; nf < 4; ++nf) {
      int col = c0 + nf * 16 + l15;
#pragma unroll
      for (int j = 0; j < 4; ++j) {
        int row = q0 + i * 16 + l4 * 4 + j;
        Sb[(size_t)row * LK + col] = acc[i][nf][j];
      }
    }
  }
}

// ---------------- k2: per-row softmax, E (bf16) written in place over S ----------------
__global__ __launch_bounds__(256) void k_sm(float* __restrict__ S,
                                            float* __restrict__ Lsum,
                                            const int* __restrict__ key_len, int b0) {
  int bl = blockIdx.y, row = blockIdx.x;
  int kl = key_len[b0 + bl];
  bool uni = (kl == 0);  // JAX: all logits equal (NEG) -> uniform over ALL keys
  float* Srow = S + ((size_t)bl * LQ + row) * LK;
  int t = threadIdx.x, lane = t & 63, w = t >> 6;
  int cbase = t * 8;
  int kend = uni ? LK : ((kl + 31) & ~31);
  __shared__ float redm[4], reds[4];
  float s[8] = {};
  bool loadit = (!uni) && (cbase < kl);
  if (loadit) {
    float4 v0 = ((const float4*)Srow)[t * 2];
    float4 v1 = ((const float4*)Srow)[t * 2 + 1];
    s[0] = v0.x; s[1] = v0.y; s[2] = v0.z; s[3] = v0.w;
    s[4] = v1.x; s[5] = v1.y; s[6] = v1.z; s[7] = v1.w;
  }
  float m = -3.4e38f;
  if (loadit) {
#pragma unroll
    for (int c = 0; c < 8; ++c)
      if (cbase + c < kl) m = fmaxf(m, s[c]);
  }
#pragma unroll
  for (int off = 32; off; off >>= 1) m = fmaxf(m, __shfl_xor(m, off));
  if (lane == 0) redm[w] = m;
  __syncthreads();
  m = fmaxf(fmaxf(redm[0], redm[1]), fmaxf(redm[2], redm[3]));
  float sum = 0.f;
  unsigned short e[8];
#pragma unroll
  for (int c = 0; c < 8; ++c) {
    float ev = uni ? 1.0f : ((loadit && (cbase + c < kl)) ? __expf(s[c] - m) : 0.0f);
    sum += ev;
    e[c] = f2bf(ev);
  }
#pragma unroll
  for (int off = 32; off; off >>= 1) sum += __shfl_xor(sum, off);
  if (lane == 0) reds[w] = sum;
  __syncthreads();  // all row reads complete before the in-place overwrite
  if (cbase < kend) {
    union { unsigned short us[8]; int4 v; } pk;
#pragma unroll
    for (int c = 0; c < 8; ++c) pk.us[c] = e[c];
    ((int4*)Srow)[t] = pk.v;  // cols [t*8, t*8+8) as bf16 in the row's first 4KB
  }
  if (t == 0) Lsum[(size_t)bl * LQ + row] = reds[0] + reds[1] + reds[2] + reds[3];
}

// ---------------- k3: O = (E * VT^T) / L  (bf16 MFMA) ----------------
__global__ __launch_bounds__(256, 2) void k_pv(const unsigned short* __restrict__ E,
                                               const unsigned short* __restrict__ VT,
                                               const float* __restrict__ Lsum,
                                               float* __restrict__ O,
                                               const int* __restrict__ key_len, int b0) {
  __shared__ short As[128 * 32], Bs[128 * 32];
  int bl = blockIdx.z;
  int kl = key_len[b0 + bl];
  int kend = (kl == 0) ? LK : ((kl + 31) & ~31);
  const int SE = LK * 2;  // E row stride in ushorts (bf16 packed over fp32 S rows)
  const unsigned short* Eb = E + (size_t)bl * LQ * LK * 2 + (size_t)blockIdx.x * 128 * SE;
  const unsigned short* Vb = VT + (size_t)bl * DD * LK + (size_t)blockIdx.y * 128 * LK;
  int t = threadIdx.x, lane = t & 63, w = t >> 6;
  int wm = w >> 1, wn = w & 1;
  int srow = t >> 2, scol = (t & 3) * 8;
  int l15 = lane & 15, l4 = lane >> 4;
  f4 acc[4][4] = {};
  for (int kk = 0; kk < kend; kk += 32) {
    gld16((char*)As + t * 16, Eb + (size_t)srow * SE + kk + scol);
    gld16((char*)As + 4096 + t * 16, Eb + (size_t)(64 + srow) * SE + kk + scol);
    gld16((char*)Bs + t * 16, Vb + (size_t)srow * LK + kk + scol);
    gld16((char*)Bs + 4096 + t * 16, Vb + (size_t)(64 + srow) * LK + kk + scol);
    __syncthreads();
    s8x a[4], b[4];
#pragma unroll
    for (int i = 0; i < 4; ++i)
      a[i] = *(const s8x*)&As[(wm * 64 + i * 16 + l15) * 32 + l4 * 8];
#pragma unroll
    for (int j = 0; j < 4; ++j)
      b[j] = *(const s8x*)&Bs[(wn * 64 + j * 16 + l15) * 32 + l4 * 8];
#pragma unroll
    for (int i = 0; i < 4; ++i)
#pragma unroll
      for (int j = 0; j < 4; ++j)
        acc[i][j] = __builtin_amdgcn_mfma_f32_16x16x32_bf16(a[i], b[j], acc[i][j], 0, 0, 0);
    __syncthreads();
  }
  int q0 = blockIdx.x * 128 + wm * 64;
  int d0 = blockIdx.y * 128 + wn * 64;
  const float* Lb = Lsum + (size_t)bl * LQ;
  float* Ob = O + (size_t)(b0 + bl) * LQ * DD;
#pragma unroll
  for (int i = 0; i < 4; ++i) {
#pragma unroll
    for (int j = 0; j < 4; ++j) {
      int row = q0 + i * 16 + l4 * 4 + j;
      float rinv = 1.0f / Lb[row];
#pragma unroll
      for (int nf = 0; nf < 4; ++nf)
        Ob[(size_t)row * DD + d0 + nf * 16 + l15] = acc[i][nf][j] * rinv;
    }
  }
}

extern "C" void kernel_launch(void* const* d_in, const int* in_sizes, int n_in,
                              void* d_out, int out_size, void* d_ws, size_t ws_size,
                              hipStream_t stream) {
  const float* Q = (const float*)d_in[0];
  const float* Kp = (const float*)d_in[1];
  const float* V = (const float*)d_in[2];
  const int* key_len = (const int*)d_in[3];
  float* O = (float*)d_out;

  const size_t szQh = (size_t)LQ * DD * sizeof(_Float16);       // 4 MiB / batch
  const size_t szKh = (size_t)LK * DD * sizeof(_Float16);       // 4 MiB / batch
  const size_t szVT = (size_t)DD * LK * sizeof(unsigned short); // 4 MiB / batch
  const size_t szS  = (size_t)LQ * LK * sizeof(float);          // 16 MiB / batch (E in-place)
  const size_t szL  = (size_t)LQ * sizeof(float);
  const size_t perb = szQh + szKh + szVT + szS + szL;

  int CB = (int)(ws_size / perb);
  if (CB > NB) CB = NB;
  if (CB < 1) CB = 1;  // assumes ws_size >= ~28 MiB

  char* base = (char*)d_ws;
  _Float16* Qh = (_Float16*)base;             base += szQh * CB;
  _Float16* Kh = (_Float16*)base;             base += szKh * CB;
  unsigned short* VT = (unsigned short*)base; base += szVT * CB;
  float* S = (float*)base;                    base += szS * CB;
  float* Lsum = (float*)base;

  for (int b0 = 0; b0 < NB; b0 += CB) {
    int nb = (NB - b0 < CB) ? (NB - b0) : CB;
    long n4 = (long)nb * LQ * DD / 4;
    k_cvt_h<<<2048, 256, 0, stream>>>(Q + (size_t)b0 * LQ * DD, Qh, n4);
    k_cvt_h<<<2048, 256, 0, stream>>>(Kp + (size_t)b0 * LK * DD, Kh, n4);
    k_vt<<<dim3(LK / 64, DD / 64, nb), 256, 0, stream>>>(V, VT, key_len, b0);
    k_qk<<<dim3(LQ / 128, LK / 128, nb), 256, 0, stream>>>(Qh, Kh, S, key_len, b0);
    k_sm<<<dim3(LQ, nb), 256, 0, stream>>>(S, Lsum, key_len, b0);
    k_pv<<<dim3(LQ / 128, DD / 128, nb), 256, 0, stream>>>((const unsigned short*)S, VT, Lsum,
                                                           O, key_len, b0);
  }
}